// Round 11
// baseline (242.283 us; speedup 1.0000x reference)
//
#include <hip/hip_runtime.h>
#include <math.h>

#define NPTS 65536  // N per batch (fixed by problem)

typedef unsigned short ushort_t;
typedef unsigned int uint_t;
typedef __attribute__((ext_vector_type(8))) short bf16x8;
typedef __attribute__((ext_vector_type(4))) float f32x4;
typedef __attribute__((ext_vector_type(2))) float f32x2;
typedef __attribute__((ext_vector_type(4))) int i32x4;
typedef __attribute__((ext_vector_type(4))) uint_t u32x4;
typedef __attribute__((ext_vector_type(2))) uint_t u32x2;

// Non-temporal (streaming) access: read-once/write-once tensors must not
// allocate in the per-XCD L2, so the random-gather TABLES stay resident
// (R10 ledger: table+streams > 4MB L2 -> gathers spill to slower L3).
template <typename T>
__device__ __forceinline__ T nt_load(const T* p) {
  return __builtin_nontemporal_load(p);
}
template <typename T>
__device__ __forceinline__ void nt_store(T* p, T v) {
  __builtin_nontemporal_store(v, p);
}

__device__ __forceinline__ float lrelu(float x) {
  return fmaxf(x, 0.2f * x);  // leaky_relu(x,0.2); exact on positive branch
}
// packed lrelu on a channel pair -> v_pk_mul + v_pk_max
__device__ __forceinline__ f32x2 lrelu2(f32x2 s) {
  return __builtin_elementwise_max(s, s * 0.2f);
}
// raw v_sqrt_f32 via intrinsic (R6: inline asm pinned live ranges; intrinsic
// keeps VGPR 40-44). Numerics validated R5-R10.
__device__ __forceinline__ float fast_sqrtf(float x) {
  return __builtin_amdgcn_sqrtf(x);
}
__device__ __forceinline__ ushort_t f2b(float f) {  // f32->bf16 RNE
  union { float f; uint_t u; } v; v.f = f;
  uint_t u = v.u + (0x7fffu + ((v.u >> 16) & 1u));
  return (ushort_t)(u >> 16);
}
__device__ __forceinline__ float b2f_lo(uint_t u) {
  union { uint_t u; float f; } v; v.u = u << 16; return v.f;
}
__device__ __forceinline__ float b2f_hi(uint_t u) {
  union { uint_t u; float f; } v; v.u = u & 0xffff0000u; return v.f;
}
// pack 2x f32x4 -> 8 bf16 (RNE)
__device__ __forceinline__ bf16x8 cvt8v(f32x4 a, f32x4 b) {
  bf16x8 r;
#pragma unroll
  for (int j = 0; j < 4; ++j) r[j] = (short)f2b(a[j]);
#pragma unroll
  for (int j = 0; j < 4; ++j) r[4 + j] = (short)f2b(b[j]);
  return r;
}

// Batch-partitioned block->point mapping: batch 0 -> XCDs 0-3, batch 1 ->
// XCDs 4-7 (blockIdx%8 is the measured XCD round-robin). Halves each XCD's
// random-gather working set (must stay < 4MB L2 -- R8 thrash lesson).
// Bijective whenever gridDim*ppb == 2*NPTS.
__device__ __forceinline__ int swz_pbase(int ppb) {
  int bid = blockIdx.x;
  if ((int)gridDim.x * ppb == 2 * NPTS) {
    int g = bid >> 3, x = bid & 7;
    return (x >> 2) * NPTS + (g * 4 + (x & 3)) * ppb;
  }
  return bid * ppb;
}

// x1 = leaky(features @ w_init^T + b_init) -> bf16 (BN,16); builds pts4;
// blocks 0/1 also prepack wf/wr to bf16 for the fused final epilogue.
__global__ __launch_bounds__(256) void k_init(
    const float* __restrict__ feats, const float* __restrict__ w,
    const float* __restrict__ bia, ushort_t* __restrict__ x1,
    const float* __restrict__ pts, float4* __restrict__ pts4,
    const float* __restrict__ wf, const float* __restrict__ wr,
    ushort_t* __restrict__ wfb, ushort_t* __restrict__ wrb, int BN) {
  __shared__ float wt[64 * 16];  // wt[i*16+o] = w[o*64+i]
  int t = threadIdx.x;
  if (blockIdx.x < 2) {  // prepack 64x64 weights to bf16 (one block each)
    const float* src = blockIdx.x ? wr : wf;
    ushort_t* dst = blockIdx.x ? wrb : wfb;
    for (int e = t; e < 4096; e += 256) dst[e] = f2b(src[e]);
  }
  for (int e = t; e < 1024; e += 256) {
    int o = e >> 6, i = e & 63;
    wt[i * 16 + o] = w[e];
  }
  __syncthreads();
  int p = blockIdx.x * 256 + t;
  if (p >= BN) return;
  const float* pp = pts + (size_t)p * 3;
  pts4[p] = make_float4(pp[0], pp[1], pp[2], 0.0f);
  float acc[16];
#pragma unroll
  for (int o = 0; o < 16; ++o) acc[o] = bia[o];
  const float4* xr4 = (const float4*)(feats + (size_t)p * 64);
#pragma unroll 4
  for (int i4 = 0; i4 < 16; ++i4) {
    float4 xv = xr4[i4];
    float xs[4] = {xv.x, xv.y, xv.z, xv.w};
#pragma unroll
    for (int s = 0; s < 4; ++s) {
      float xi = xs[s];
      const float4* w4 = (const float4*)&wt[(i4 * 4 + s) * 16];
#pragma unroll
      for (int q = 0; q < 4; ++q) {
        float4 wv = w4[q];
        acc[q * 4 + 0] = fmaf(xi, wv.x, acc[q * 4 + 0]);
        acc[q * 4 + 1] = fmaf(xi, wv.y, acc[q * 4 + 1]);
        acc[q * 4 + 2] = fmaf(xi, wv.z, acc[q * 4 + 2]);
        acc[q * 4 + 3] = fmaf(xi, wv.w, acc[q * 4 + 3]);
      }
    }
  }
  union { ushort_t u[16]; uint4 v[2]; } pk;
#pragma unroll
  for (int o = 0; o < 16; ++o) pk.u[o] = f2b(lrelu(acc[o]));
  uint4* op = (uint4*)(x1 + (size_t)p * 16);
  op[0] = pk.v[0];
  op[1] = pk.v[1];
}

// LFA1 + LFA2-geometry fusion, 8 lanes/point (32 points per 256-thr block).
// Lane sub owns: lfa1 ch [sub*2,+2), lfa2-geo ch [sub*4,+4), feat ch [sub*2,+2).
// R11: idx loads + x2/g2 stores NON-TEMPORAL -> pts4/x1 tables (3MB/batch)
// own the XCD L2; gathers hit L2 (~200cy) instead of spilling to L3 (~450cy).
// Table accesses (pts4[j], x1[j]) stay cached.
__global__ __launch_bounds__(256) void k_lfa1g(
    const float4* __restrict__ pts4, const ushort_t* __restrict__ fin,
    const int* __restrict__ idx, const float* __restrict__ w1,
    const float* __restrict__ b1, const float* __restrict__ w2,
    const float* __restrict__ b2, ushort_t* __restrict__ x2out,
    ushort_t* __restrict__ g2out, int BN) {
  int t = threadIdx.x;
  int p = swz_pbase(32) + (t >> 3);
  int sub = t & 7;
  if (p >= BN) return;
  int base = p & ~(NPTS - 1);
  float4 mp = pts4[p];
  // lfa1 pair: rows sub*2, sub*2+1 (4 weights each), packed per-k
  const float* w1b = w1 + sub * 8;
  f32x2 w1p[4], b1p;
#pragma unroll
  for (int k = 0; k < 4; ++k) w1p[k] = f32x2{w1b[k], w1b[4 + k]};
  b1p = f32x2{b1[sub * 2], b1[sub * 2 + 1]};
  // lfa2 pairs: rows sub*4 .. sub*4+3
  const float* w2b = w2 + sub * 16;
  f32x2 w2p[2][4], b2p[2];
#pragma unroll
  for (int pr = 0; pr < 2; ++pr) {
#pragma unroll
    for (int k = 0; k < 4; ++k)
      w2p[pr][k] = f32x2{w2b[pr * 8 + k], w2b[pr * 8 + 4 + k]};
    b2p[pr] = f32x2{b2[sub * 4 + pr * 2], b2[sub * 4 + pr * 2 + 1]};
  }
  f32x2 m1 = {0.f, 0.f}, f1 = {0.f, 0.f};
  f32x2 m2[2] = {{0.f, 0.f}, {0.f, 0.f}};
  const i32x4* iv4 = (const i32x4*)(idx + (size_t)p * 32);
#pragma unroll 4
  for (int kk = 0; kk < 8; ++kk) {
    i32x4 iv = nt_load(&iv4[kk]);  // streaming: no L2 allocation
    int js[4] = {iv[0], iv[1], iv[2], iv[3]};
#pragma unroll
    for (int u = 0; u < 4; ++u) {
      int j = base + js[u];
      float4 pj = pts4[j];
      uint_t fv = *((const uint_t*)(fin + (size_t)j * 16) + sub);  // 2 bf16
      float rx = mp.x - pj.x, ry = mp.y - pj.y, rz = mp.z - pj.z;
      float d = fast_sqrtf(fmaf(rx, rx, fmaf(ry, ry, rz * rz)));
      f32x2 vx = {rx, rx}, vy = {ry, ry}, vz = {rz, rz}, vd = {d, d};
      // same fma order as scalar version: b + d*w3, +rz*w2, +ry*w1, +rx*w0
      f32x2 s = __builtin_elementwise_fma(vd, w1p[3], b1p);
      s = __builtin_elementwise_fma(vz, w1p[2], s);
      s = __builtin_elementwise_fma(vy, w1p[1], s);
      s = __builtin_elementwise_fma(vx, w1p[0], s);
      m1 += lrelu2(s);
#pragma unroll
      for (int pr = 0; pr < 2; ++pr) {
        f32x2 s2 = __builtin_elementwise_fma(vd, w2p[pr][3], b2p[pr]);
        s2 = __builtin_elementwise_fma(vz, w2p[pr][2], s2);
        s2 = __builtin_elementwise_fma(vy, w2p[pr][1], s2);
        s2 = __builtin_elementwise_fma(vx, w2p[pr][0], s2);
        m2[pr] += lrelu2(s2);
      }
      f1 += f32x2{b2f_lo(fv), b2f_hi(fv)};
    }
  }
  const float inv = 1.0f / 32.0f;
  ushort_t* orow = x2out + (size_t)p * 32;
  union { ushort_t u[2]; uint_t v; } pm, pf;
  pm.u[0] = f2b(m1.x * inv); pm.u[1] = f2b(m1.y * inv);
  pf.u[0] = f2b(f1.x * inv); pf.u[1] = f2b(f1.y * inv);
  nt_store((uint_t*)orow + sub, pm.v);       // MLP section ch [sub*2,+2)
  nt_store((uint_t*)orow + 8 + sub, pf.v);   // feat section ch [16+sub*2,+2)
  union { ushort_t u[4]; u32x2 v; } pg;
  pg.u[0] = f2b(m2[0].x * inv); pg.u[1] = f2b(m2[0].y * inv);
  pg.u[2] = f2b(m2[1].x * inv); pg.u[3] = f2b(m2[1].y * inv);
  nt_store((u32x2*)(g2out + (size_t)p * 32) + sub, pg.v);  // ch [sub*4,+4)
}

// LFA2 gather + fused final: x2 bf16 (BN,32), g2 bf16 (BN,32) -> out f32 (BN,64).
// Weights staged in LDS (144B row pad, R10: +4.5us). R11: idx/g2/feats loads
// + out stores non-temporal so the x2 table (4MB/batch = L2 size) stays
// resident. x2 gathers stay cached.
// g2 slice / facc*inv are EXACTLY the 16x16x32 bf16 MFMA A-fragments
// (row=lane&15, k=(lane>>4)*8+j) for k in [0,32)/[32,64).
__global__ __launch_bounds__(128) void k_lfa2f(
    const ushort_t* __restrict__ fin, const int* __restrict__ idx,
    const ushort_t* __restrict__ g2, const float* __restrict__ feats,
    const ushort_t* __restrict__ wfb, const float* __restrict__ bfi,
    const ushort_t* __restrict__ wrb, const float* __restrict__ bri,
    float* __restrict__ out, int BN) {
  // wl[plane][row*72 + slot*8]: row stride 144B -> 2-way bank aliasing only.
  __shared__ ushort_t wl[2][64 * 72];
  int t = threadIdx.x;
  {
    const uint4* s0 = (const uint4*)wfb;
    const uint4* s1 = (const uint4*)wrb;
    for (int e = t; e < 512; e += 128) {
      int row = e >> 3, slot = e & 7;
      *(uint4*)(&wl[0][row * 72 + slot * 8]) = s0[e];
      *(uint4*)(&wl[1][row * 72 + slot * 8]) = s1[e];
    }
  }
  __syncthreads();
  int lane = t & 63, wave = t >> 6;
  int n = lane & 15, quad = lane >> 4;
  int wbase = swz_pbase(32) + wave * 16;
  int p0 = wbase + n;
  int p = p0 < BN ? p0 : BN - 1;  // clamp: all 64 lanes must reach the MFMAs
  int base = p & ~(NPTS - 1);
  f32x2 fa[4];
#pragma unroll
  for (int o = 0; o < 4; ++o) fa[o] = f32x2{0.f, 0.f};
  const i32x4* iv4 = (const i32x4*)(idx + (size_t)p * 32);
#pragma unroll 8
  for (int kk = 0; kk < 8; ++kk) {
    i32x4 iv = nt_load(&iv4[kk]);  // streaming
    int js[4] = {iv[0], iv[1], iv[2], iv[3]};
#pragma unroll
    for (int u = 0; u < 4; ++u) {
      int j = base + js[u];
      // x2 gather: TABLE access, keep cached
      u32x4 fv = *((const u32x4*)(fin + (size_t)j * 32) + quad);  // 8 bf16
      fa[0] += f32x2{b2f_lo(fv[0]), b2f_hi(fv[0])};
      fa[1] += f32x2{b2f_lo(fv[1]), b2f_hi(fv[1])};
      fa[2] += f32x2{b2f_lo(fv[2]), b2f_hi(fv[2])};
      fa[3] += f32x2{b2f_lo(fv[3]), b2f_hi(fv[3])};
    }
  }
  // ---- fused final: A-fragments from g2 (precomputed geo-MLP) + facc ----
  const float inv = 1.0f / 32.0f;
  bf16x8 Ax0 = nt_load((const bf16x8*)(g2 + (size_t)p * 32 + quad * 8));
  bf16x8 Ax1;
#pragma unroll
  for (int o = 0; o < 4; ++o) {
    Ax1[o * 2 + 0] = (short)f2b(fa[o].x * inv);
    Ax1[o * 2 + 1] = (short)f2b(fa[o].y * inv);
  }
  const f32x4* af = (const f32x4*)(feats + (size_t)p * 64 + quad * 8);
  bf16x8 Af0 = cvt8v(nt_load(af), nt_load(af + 1));
  const f32x4* af2 = (const f32x4*)(feats + (size_t)p * 64 + 32 + quad * 8);
  bf16x8 Af1 = cvt8v(nt_load(af2), nt_load(af2 + 1));
#pragma unroll
  for (int nt_ = 0; nt_ < 4; ++nt_) {
    int lrow = (nt_ * 16 + n) * 72 + quad * 8;
    bf16x8 Bf0 = *((const bf16x8*)(&wl[0][lrow]));
    bf16x8 Bf1 = *((const bf16x8*)(&wl[0][lrow + 32]));
    f32x4 accx = {0.f, 0.f, 0.f, 0.f};
    accx = __builtin_amdgcn_mfma_f32_16x16x32_bf16(Ax0, Bf0, accx, 0, 0, 0);
    accx = __builtin_amdgcn_mfma_f32_16x16x32_bf16(Ax1, Bf1, accx, 0, 0, 0);
    bf16x8 Br0 = *((const bf16x8*)(&wl[1][lrow]));
    bf16x8 Br1 = *((const bf16x8*)(&wl[1][lrow + 32]));
    f32x4 accr = {0.f, 0.f, 0.f, 0.f};
    accr = __builtin_amdgcn_mfma_f32_16x16x32_bf16(Af0, Br0, accr, 0, 0, 0);
    accr = __builtin_amdgcn_mfma_f32_16x16x32_bf16(Af1, Br1, accr, 0, 0, 0);
    float bvf = bfi[nt_ * 16 + n];
    float bvr = bri[nt_ * 16 + n];
#pragma unroll
    for (int r = 0; r < 4; ++r) {
      int row = wbase + quad * 4 + r;  // C/D: col=lane&15, row=quad*4+r
      if (row < BN)
        nt_store(out + (size_t)row * 64 + nt_ * 16 + n,
                 lrelu(accx[r] + bvf) + lrelu(accr[r] + bvr));
    }
  }
}

extern "C" void kernel_launch(void* const* d_in, const int* in_sizes, int n_in,
                              void* d_out, int out_size, void* d_ws, size_t ws_size,
                              hipStream_t stream) {
  const float* pts    = (const float*)d_in[0];
  const float* feats  = (const float*)d_in[1];
  const int*   idx    = (const int*)d_in[2];
  const float* w_init = (const float*)d_in[3];
  const float* b_init = (const float*)d_in[4];
  const float* w_l1   = (const float*)d_in[5];
  const float* b_l1   = (const float*)d_in[6];
  const float* w_l2   = (const float*)d_in[7];
  const float* b_l2   = (const float*)d_in[8];
  const float* w_f    = (const float*)d_in[9];
  const float* b_f    = (const float*)d_in[10];
  const float* w_r    = (const float*)d_in[11];
  const float* b_r    = (const float*)d_in[12];
  float* out = (float*)d_out;

  int BN = in_sizes[2] / 32;  // B*N = 131072
  // ws: x1 bf16 (4 MB) | x2 bf16 (8 MB) | pts4 (2 MB) | wfb/wrb (16 KB) | g2 (8 MB)
  ushort_t* x1 = (ushort_t*)d_ws;
  ushort_t* x2 = x1 + (size_t)BN * 16;
  float4* pts4 = (float4*)(x2 + (size_t)BN * 32);
  ushort_t* wfb = (ushort_t*)(pts4 + BN);
  ushort_t* wrb = wfb + 4096;
  ushort_t* g2 = wrb + 4096;

  int blocks_pt = (BN + 255) / 256;
  int blocks_l1 = (BN + 31) / 32;   // 32 points/block (8 lanes/point, 256 thr)
  int blocks_l2 = (BN + 31) / 32;   // 32 points/block (4 lanes/point, 128 thr)

  k_init<<<blocks_pt, 256, 0, stream>>>(feats, w_init, b_init, x1, pts, pts4,
                                        w_f, w_r, wfb, wrb, BN);
  k_lfa1g<<<blocks_l1, 256, 0, stream>>>(pts4, x1, idx, w_l1, b_l1, w_l2, b_l2,
                                         x2, g2, BN);
  k_lfa2f<<<blocks_l2, 128, 0, stream>>>(x2, idx, g2, feats, wfb, b_f, wrb, b_r,
                                         out, BN);
}

// Round 12
// 217.713 us; speedup vs baseline: 1.1129x; 1.1129x over previous
//
#include <hip/hip_runtime.h>
#include <math.h>

#define NPTS 65536  // N per batch (fixed by problem)

typedef unsigned short ushort_t;
typedef unsigned int uint_t;
typedef __attribute__((ext_vector_type(8))) short bf16x8;
typedef __attribute__((ext_vector_type(4))) float f32x4;
typedef __attribute__((ext_vector_type(2))) float f32x2;

__device__ __forceinline__ float lrelu(float x) {
  return fmaxf(x, 0.2f * x);  // leaky_relu(x,0.2); exact on positive branch
}
// packed lrelu on a channel pair -> v_pk_mul + v_pk_max
__device__ __forceinline__ f32x2 lrelu2(f32x2 s) {
  return __builtin_elementwise_max(s, s * 0.2f);
}
// raw v_sqrt_f32 via intrinsic (R6: inline asm pinned live ranges; intrinsic
// keeps VGPR 40-44). Numerics validated R5-R11.
__device__ __forceinline__ float fast_sqrtf(float x) {
  return __builtin_amdgcn_sqrtf(x);
}
__device__ __forceinline__ ushort_t f2b(float f) {  // f32->bf16 RNE
  union { float f; uint_t u; } v; v.f = f;
  uint_t u = v.u + (0x7fffu + ((v.u >> 16) & 1u));
  return (ushort_t)(u >> 16);
}
__device__ __forceinline__ float b2f_lo(uint_t u) {
  union { uint_t u; float f; } v; v.u = u << 16; return v.f;
}
__device__ __forceinline__ float b2f_hi(uint_t u) {
  union { uint_t u; float f; } v; v.u = u & 0xffff0000u; return v.f;
}
// pack 8 consecutive f32 -> 8 bf16 (RNE)
__device__ __forceinline__ bf16x8 cvt8(const float* p) {
  float4 a = ((const float4*)p)[0];
  float4 b = ((const float4*)p)[1];
  float f[8] = {a.x, a.y, a.z, a.w, b.x, b.y, b.z, b.w};
  bf16x8 r;
#pragma unroll
  for (int j = 0; j < 8; ++j) r[j] = (short)f2b(f[j]);
  return r;
}

// Batch-partitioned block->point mapping: batch 0 -> XCDs 0-3, batch 1 ->
// XCDs 4-7 (blockIdx%8 is the measured XCD round-robin). Halves each XCD's
// random-gather working set (must stay < 4MB L2 -- R8 thrash lesson).
// Bijective whenever gridDim*ppb == 2*NPTS.
// R11 lesson: NO non-temporal hints -- nt stores bypass L2 write-combining
// (+3us lfa1g) and nt loads inflate latency (+~7us lfa2f). Reverted.
__device__ __forceinline__ int swz_pbase(int ppb) {
  int bid = blockIdx.x;
  if ((int)gridDim.x * ppb == 2 * NPTS) {
    int g = bid >> 3, x = bid & 7;
    return (x >> 2) * NPTS + (g * 4 + (x & 3)) * ppb;
  }
  return bid * ppb;
}

// x1 = leaky(features @ w_init^T + b_init) -> bf16 (BN,16); builds pts4;
// blocks 0/1 also prepack wf/wr to bf16 for the fused final epilogue.
__global__ __launch_bounds__(256) void k_init(
    const float* __restrict__ feats, const float* __restrict__ w,
    const float* __restrict__ bia, ushort_t* __restrict__ x1,
    const float* __restrict__ pts, float4* __restrict__ pts4,
    const float* __restrict__ wf, const float* __restrict__ wr,
    ushort_t* __restrict__ wfb, ushort_t* __restrict__ wrb, int BN) {
  __shared__ float wt[64 * 16];  // wt[i*16+o] = w[o*64+i]
  int t = threadIdx.x;
  if (blockIdx.x < 2) {  // prepack 64x64 weights to bf16 (one block each)
    const float* src = blockIdx.x ? wr : wf;
    ushort_t* dst = blockIdx.x ? wrb : wfb;
    for (int e = t; e < 4096; e += 256) dst[e] = f2b(src[e]);
  }
  for (int e = t; e < 1024; e += 256) {
    int o = e >> 6, i = e & 63;
    wt[i * 16 + o] = w[e];
  }
  __syncthreads();
  int p = blockIdx.x * 256 + t;
  if (p >= BN) return;
  const float* pp = pts + (size_t)p * 3;
  pts4[p] = make_float4(pp[0], pp[1], pp[2], 0.0f);
  float acc[16];
#pragma unroll
  for (int o = 0; o < 16; ++o) acc[o] = bia[o];
  const float4* xr4 = (const float4*)(feats + (size_t)p * 64);
#pragma unroll 4
  for (int i4 = 0; i4 < 16; ++i4) {
    float4 xv = xr4[i4];
    float xs[4] = {xv.x, xv.y, xv.z, xv.w};
#pragma unroll
    for (int s = 0; s < 4; ++s) {
      float xi = xs[s];
      const float4* w4 = (const float4*)&wt[(i4 * 4 + s) * 16];
#pragma unroll
      for (int q = 0; q < 4; ++q) {
        float4 wv = w4[q];
        acc[q * 4 + 0] = fmaf(xi, wv.x, acc[q * 4 + 0]);
        acc[q * 4 + 1] = fmaf(xi, wv.y, acc[q * 4 + 1]);
        acc[q * 4 + 2] = fmaf(xi, wv.z, acc[q * 4 + 2]);
        acc[q * 4 + 3] = fmaf(xi, wv.w, acc[q * 4 + 3]);
      }
    }
  }
  union { ushort_t u[16]; uint4 v[2]; } pk;
#pragma unroll
  for (int o = 0; o < 16; ++o) pk.u[o] = f2b(lrelu(acc[o]));
  uint4* op = (uint4*)(x1 + (size_t)p * 16);
  op[0] = pk.v[0];
  op[1] = pk.v[1];
}

// LFA1 + LFA2-geometry fusion, 8 lanes/point (32 points per 256-thr block).
// Lane sub owns: lfa1 ch [sub*2,+2), lfa2-geo ch [sub*4,+4), feat ch [sub*2,+2).
// Exact R10 configuration (best measured: 62-64us, FETCH 27MB, VGPR 44).
__global__ __launch_bounds__(256) void k_lfa1g(
    const float4* __restrict__ pts4, const ushort_t* __restrict__ fin,
    const int* __restrict__ idx, const float* __restrict__ w1,
    const float* __restrict__ b1, const float* __restrict__ w2,
    const float* __restrict__ b2, ushort_t* __restrict__ x2out,
    ushort_t* __restrict__ g2out, int BN) {
  int t = threadIdx.x;
  int p = swz_pbase(32) + (t >> 3);
  int sub = t & 7;
  if (p >= BN) return;
  int base = p & ~(NPTS - 1);
  float4 mp = pts4[p];
  // lfa1 pair: rows sub*2, sub*2+1 (4 weights each), packed per-k
  const float* w1b = w1 + sub * 8;
  f32x2 w1p[4], b1p;
#pragma unroll
  for (int k = 0; k < 4; ++k) w1p[k] = f32x2{w1b[k], w1b[4 + k]};
  b1p = f32x2{b1[sub * 2], b1[sub * 2 + 1]};
  // lfa2 pairs: rows sub*4 .. sub*4+3
  const float* w2b = w2 + sub * 16;
  f32x2 w2p[2][4], b2p[2];
#pragma unroll
  for (int pr = 0; pr < 2; ++pr) {
#pragma unroll
    for (int k = 0; k < 4; ++k)
      w2p[pr][k] = f32x2{w2b[pr * 8 + k], w2b[pr * 8 + 4 + k]};
    b2p[pr] = f32x2{b2[sub * 4 + pr * 2], b2[sub * 4 + pr * 2 + 1]};
  }
  f32x2 m1 = {0.f, 0.f}, f1 = {0.f, 0.f};
  f32x2 m2[2] = {{0.f, 0.f}, {0.f, 0.f}};
  const int4* iv4 = (const int4*)(idx + (size_t)p * 32);
#pragma unroll 4
  for (int kk = 0; kk < 8; ++kk) {
    int4 iv = iv4[kk];
    int js[4] = {iv.x, iv.y, iv.z, iv.w};
#pragma unroll
    for (int u = 0; u < 4; ++u) {
      int j = base + js[u];
      float4 pj = pts4[j];
      uint_t fv = *((const uint_t*)(fin + (size_t)j * 16) + sub);  // 2 bf16
      float rx = mp.x - pj.x, ry = mp.y - pj.y, rz = mp.z - pj.z;
      float d = fast_sqrtf(fmaf(rx, rx, fmaf(ry, ry, rz * rz)));
      f32x2 vx = {rx, rx}, vy = {ry, ry}, vz = {rz, rz}, vd = {d, d};
      // same fma order as scalar version: b + d*w3, +rz*w2, +ry*w1, +rx*w0
      f32x2 s = __builtin_elementwise_fma(vd, w1p[3], b1p);
      s = __builtin_elementwise_fma(vz, w1p[2], s);
      s = __builtin_elementwise_fma(vy, w1p[1], s);
      s = __builtin_elementwise_fma(vx, w1p[0], s);
      m1 += lrelu2(s);
#pragma unroll
      for (int pr = 0; pr < 2; ++pr) {
        f32x2 s2 = __builtin_elementwise_fma(vd, w2p[pr][3], b2p[pr]);
        s2 = __builtin_elementwise_fma(vz, w2p[pr][2], s2);
        s2 = __builtin_elementwise_fma(vy, w2p[pr][1], s2);
        s2 = __builtin_elementwise_fma(vx, w2p[pr][0], s2);
        m2[pr] += lrelu2(s2);
      }
      f1 += f32x2{b2f_lo(fv), b2f_hi(fv)};
    }
  }
  const float inv = 1.0f / 32.0f;
  ushort_t* orow = x2out + (size_t)p * 32;
  union { ushort_t u[2]; uint_t v; } pm, pf;
  pm.u[0] = f2b(m1.x * inv); pm.u[1] = f2b(m1.y * inv);
  pf.u[0] = f2b(f1.x * inv); pf.u[1] = f2b(f1.y * inv);
  ((uint_t*)orow)[sub] = pm.v;       // MLP section ch [sub*2,+2)
  ((uint_t*)orow)[8 + sub] = pf.v;   // feat section ch [16+sub*2,+2)
  union { ushort_t u[4]; uint2 v; } pg;
  pg.u[0] = f2b(m2[0].x * inv); pg.u[1] = f2b(m2[0].y * inv);
  pg.u[2] = f2b(m2[1].x * inv); pg.u[3] = f2b(m2[1].y * inv);
  ((uint2*)(g2out + (size_t)p * 32))[sub] = pg.v;  // lfa2 mlp ch [sub*4,+4)
}

// LFA2 gather + fused final: x2 bf16 (BN,32), g2 bf16 (BN,32) -> out f32 (BN,64).
// R12: CONFLICT-FREE permuted LDS weight layout. Lane (n,quad)'s fragment for
// (nt,half) lives at entry (nt*128 + half*64 + lane): read addr = lane*16+const
// -> canonical conflict-free full-wave ds_read_b128 (R11 measured 524K
// conflicts with the 144B-pad layout: bank group 4(n+quad)%32 = 8-way).
// 256-thr blocks: 4 waves share one 16KB staging -> LDS no longer caps
// occupancy (R11: 18.4KB x 128-thr capped at 33%).
// g2 slice / facc*inv are EXACTLY the 16x16x32 bf16 MFMA A-fragments
// (row=lane&15, k=(lane>>4)*8+j) for k in [0,32)/[32,64).
__global__ __launch_bounds__(256) void k_lfa2f(
    const ushort_t* __restrict__ fin, const int* __restrict__ idx,
    const ushort_t* __restrict__ g2, const float* __restrict__ feats,
    const ushort_t* __restrict__ wfb, const float* __restrict__ bfi,
    const ushort_t* __restrict__ wrb, const float* __restrict__ bri,
    float* __restrict__ out, int BN) {
  // wl[plane][entry*8] ushorts, entry = nt*128 + half*64 + quad*16 + n
  __shared__ ushort_t wl[2][512 * 8];
  int t = threadIdx.x;
  for (int e = t; e < 512; e += 256) {
    int nt_ = e >> 7, half = (e >> 6) & 1, le = e & 63;
    int q_ = le >> 4, n_ = le & 15;
    int src = (nt_ * 16 + n_) * 64 + half * 32 + q_ * 8;
    *(uint4*)(&wl[0][e * 8]) = *(const uint4*)(wfb + src);
    *(uint4*)(&wl[1][e * 8]) = *(const uint4*)(wrb + src);
  }
  __syncthreads();
  int lane = t & 63, wave = t >> 6;
  int n = lane & 15, quad = lane >> 4;
  int wbase = swz_pbase(64) + wave * 16;
  int p0 = wbase + n;
  int p = p0 < BN ? p0 : BN - 1;  // clamp: all 64 lanes must reach the MFMAs
  int base = p & ~(NPTS - 1);
  f32x2 fa[4];
#pragma unroll
  for (int o = 0; o < 4; ++o) fa[o] = f32x2{0.f, 0.f};
  const int4* iv4 = (const int4*)(idx + (size_t)p * 32);
#pragma unroll 8
  for (int kk = 0; kk < 8; ++kk) {
    int4 iv = iv4[kk];
    int js[4] = {iv.x, iv.y, iv.z, iv.w};
#pragma unroll
    for (int u = 0; u < 4; ++u) {
      int j = base + js[u];
      uint4 fv = *((const uint4*)(fin + (size_t)j * 32) + quad);  // 8 bf16
      fa[0] += f32x2{b2f_lo(fv.x), b2f_hi(fv.x)};
      fa[1] += f32x2{b2f_lo(fv.y), b2f_hi(fv.y)};
      fa[2] += f32x2{b2f_lo(fv.z), b2f_hi(fv.z)};
      fa[3] += f32x2{b2f_lo(fv.w), b2f_hi(fv.w)};
    }
  }
  // ---- fused final: A-fragments from g2 (precomputed geo-MLP) + facc ----
  const float inv = 1.0f / 32.0f;
  bf16x8 Ax0 = *((const bf16x8*)(g2 + (size_t)p * 32 + quad * 8));
  bf16x8 Ax1;
#pragma unroll
  for (int o = 0; o < 4; ++o) {
    Ax1[o * 2 + 0] = (short)f2b(fa[o].x * inv);
    Ax1[o * 2 + 1] = (short)f2b(fa[o].y * inv);
  }
  const float* af = feats + (size_t)p * 64 + quad * 8;
  bf16x8 Af0 = cvt8(af), Af1 = cvt8(af + 32);
#pragma unroll
  for (int nt_ = 0; nt_ < 4; ++nt_) {
    bf16x8 Bf0 = *((const bf16x8*)(&wl[0][(nt_ * 128 + lane) * 8]));
    bf16x8 Bf1 = *((const bf16x8*)(&wl[0][(nt_ * 128 + 64 + lane) * 8]));
    f32x4 accx = {0.f, 0.f, 0.f, 0.f};
    accx = __builtin_amdgcn_mfma_f32_16x16x32_bf16(Ax0, Bf0, accx, 0, 0, 0);
    accx = __builtin_amdgcn_mfma_f32_16x16x32_bf16(Ax1, Bf1, accx, 0, 0, 0);
    bf16x8 Br0 = *((const bf16x8*)(&wl[1][(nt_ * 128 + lane) * 8]));
    bf16x8 Br1 = *((const bf16x8*)(&wl[1][(nt_ * 128 + 64 + lane) * 8]));
    f32x4 accr = {0.f, 0.f, 0.f, 0.f};
    accr = __builtin_amdgcn_mfma_f32_16x16x32_bf16(Af0, Br0, accr, 0, 0, 0);
    accr = __builtin_amdgcn_mfma_f32_16x16x32_bf16(Af1, Br1, accr, 0, 0, 0);
    float bvf = bfi[nt_ * 16 + n];
    float bvr = bri[nt_ * 16 + n];
#pragma unroll
    for (int r = 0; r < 4; ++r) {
      int row = wbase + quad * 4 + r;  // C/D: col=lane&15, row=quad*4+r
      if (row < BN)
        out[(size_t)row * 64 + nt_ * 16 + n] =
            lrelu(accx[r] + bvf) + lrelu(accr[r] + bvr);
    }
  }
}

extern "C" void kernel_launch(void* const* d_in, const int* in_sizes, int n_in,
                              void* d_out, int out_size, void* d_ws, size_t ws_size,
                              hipStream_t stream) {
  const float* pts    = (const float*)d_in[0];
  const float* feats  = (const float*)d_in[1];
  const int*   idx    = (const int*)d_in[2];
  const float* w_init = (const float*)d_in[3];
  const float* b_init = (const float*)d_in[4];
  const float* w_l1   = (const float*)d_in[5];
  const float* b_l1   = (const float*)d_in[6];
  const float* w_l2   = (const float*)d_in[7];
  const float* b_l2   = (const float*)d_in[8];
  const float* w_f    = (const float*)d_in[9];
  const float* b_f    = (const float*)d_in[10];
  const float* w_r    = (const float*)d_in[11];
  const float* b_r    = (const float*)d_in[12];
  float* out = (float*)d_out;

  int BN = in_sizes[2] / 32;  // B*N = 131072
  // ws: x1 bf16 (4 MB) | x2 bf16 (8 MB) | pts4 (2 MB) | wfb/wrb (16 KB) | g2 (8 MB)
  ushort_t* x1 = (ushort_t*)d_ws;
  ushort_t* x2 = x1 + (size_t)BN * 16;
  float4* pts4 = (float4*)(x2 + (size_t)BN * 32);
  ushort_t* wfb = (ushort_t*)(pts4 + BN);
  ushort_t* wrb = wfb + 4096;
  ushort_t* g2 = wrb + 4096;

  int blocks_pt = (BN + 255) / 256;
  int blocks_l1 = (BN + 31) / 32;   // 32 points/block (8 lanes/point, 256 thr)
  int blocks_l2 = (BN + 63) / 64;   // 64 points/block (4 lanes/point, 256 thr)

  k_init<<<blocks_pt, 256, 0, stream>>>(feats, w_init, b_init, x1, pts, pts4,
                                        w_f, w_r, wfb, wrb, BN);
  k_lfa1g<<<blocks_l1, 256, 0, stream>>>(pts4, x1, idx, w_l1, b_l1, w_l2, b_l2,
                                         x2, g2, BN);
  k_lfa2f<<<blocks_l2, 256, 0, stream>>>(x2, idx, g2, feats, wfb, b_f, wrb, b_r,
                                         out, BN);
}